// Round 16
// baseline (630.412 us; speedup 1.0000x reference)
//
#include <hip/hip_runtime.h>

#define TT 512
#define L2E  1.4426950408889634f
#define L2E2 2.8853900817779268f

typedef _Float16 f16;
typedef _Float16 f16x8 __attribute__((ext_vector_type(8)));
typedef float f32x4 __attribute__((ext_vector_type(4)));

__device__ __forceinline__ float fsig_p(float a){          // sigmoid, a = x*log2e
    return __builtin_amdgcn_rcpf(1.f + __builtin_amdgcn_exp2f(-a));
}
__device__ __forceinline__ float ftanhg_p(float a){        // tanh, a = x*2log2e
    return 2.f * __builtin_amdgcn_rcpf(1.f + __builtin_amdgcn_exp2f(-a)) - 1.f;
}
__device__ __forceinline__ float ftanh_c(float c){         // tanh, unscaled input
    return 2.f * __builtin_amdgcn_rcpf(1.f + __builtin_amdgcn_exp2f(-L2E2*c)) - 1.f;
}

#define FMA_LO(accv, wd, hh) asm("v_fma_mix_f32 %0, %1, %2, %0 op_sel:[0,0,0] op_sel_hi:[1,0,0]" : "+v"(accv) : "v"(wd), "v"(hh))
#define FMA_HI(accv, wd, hh) asm("v_fma_mix_f32 %0, %1, %2, %0 op_sel:[1,0,0] op_sel_hi:[1,0,0]" : "+v"(accv) : "v"(wd), "v"(hh))

// Wp (f16): [13 m][2 kt][64 lane][8 b] A-fragments for mfma_f32_16x16x32_f16
//   row r = m*16 + (lane&15), r = 4*u+g unit-major; k = kt*32 + (lane>>4)*8 + b
//   col 0..50 = Whh1; col 51 = Wih1; col 52 = bih1+bhh1; col 53..63 = 0; rows u>=51 all 0
//   values prescaled by log2e (gates i,f,o) / 2log2e (gate g) for exp2-direct nonlinearities.
// Wp2 (f16): [56 u][4 g] = Wih2[g*51+u] prescaled likewise, zero-padded
__global__ void repack_w(const float* __restrict__ Whh1, const float* __restrict__ Wih1,
                         const float* __restrict__ bih1, const float* __restrict__ bhh1,
                         const float* __restrict__ Wih2,
                         f16* __restrict__ Wp, f16* __restrict__ Wp2)
{
    int i = blockIdx.x*256 + threadIdx.x;
    if (i < 13*2*64*8) {
        int b    = i & 7;
        int lane = (i >> 3) & 63;
        int kt   = (i >> 9) & 1;
        int m    = i >> 10;
        int r = m*16 + (lane & 15);
        int u = r >> 2, g = r & 3;
        int k = kt*32 + (lane >> 4)*8 + b;
        float v = 0.f;
        if (u < 51) {
            int rt = g*51 + u;
            if      (k < 51)  v = Whh1[rt*51 + k];
            else if (k == 51) v = Wih1[rt];
            else if (k == 52) v = bih1[rt] + bhh1[rt];
            v *= (g == 2) ? L2E2 : L2E;
        }
        Wp[i] = (f16)v;
    }
    if (i < 224) {
        int u = i >> 2, g = i & 3;
        float v = (u < 51) ? Wih2[g*51 + u] : 0.f;
        v *= (g == 2) ? L2E2 : L2E;
        Wp2[i] = (f16)v;
    }
}

// READ phase of group G, step t: B-frags = h_G(t); w3: PBL partials(t-1); w0: x(t+1)
#define RD_PHASE(HBg, PBLg, rowoff, tn, B0v, B1v, S0v, S1v, S2v, S3v, xnv) do {  \
    const f16* rb_ = (HBg) + jl*64;                                              \
    B0v = *(const f16x8*)(rb_ + ((q       ^ d8) << 3));                          \
    B1v = *(const f16x8*)(rb_ + (((4 + q) ^ d8) << 3));                          \
    if (w == 3) {                                                                \
        S0v = *(const f32x4*)&(PBLg)[0][jl][0];                                  \
        S1v = *(const f32x4*)&(PBLg)[1][jl][0];                                  \
        S2v = *(const f32x4*)&(PBLg)[2][jl][0];                                  \
        S3v = *(const f32x4*)&(PBLg)[3][jl][0];                                  \
    }                                                                            \
    if (w == 0) xnv = HX[(tn)*32 + (rowoff) + jl];                               \
} while (0)

// WRITE phase of group G, step t: MFMA+epilogue -> h_G(t+1), partials; w3: L2(t-1)
#define WR_PHASE(doL2, HBg, PBLg, B0v, B1v, S0v, S1v, S2v, S3v, xnv, c1v, c2v, h2v) do { \
    if (w == 3 && (doL2)) {                                                      \
        f32x4 Ss_ = S0v + S1v + S2v + S3v;                                       \
        float g0_ = Ss_[0] + bs2[0] + wh2[0]*h2v;                                \
        float g1_ = Ss_[1] + bs2[1] + wh2[1]*h2v;                                \
        float g2_ = Ss_[2] + bs2[2] + wh2[2]*h2v;                                \
        float g3_ = Ss_[3] + bs2[3] + wh2[3]*h2v;                                \
        float i2_ = fsig_p(g0_), f2_ = fsig_p(g1_);                              \
        float gg2_ = ftanhg_p(g2_), o2_ = fsig_p(g3_);                           \
        c2v = f2_*c2v + i2_*gg2_;                                                \
        h2v = o2_*ftanh_c(c2v);                                                  \
    }                                                                            \
    float p0_ = 0.f, p1_ = 0.f, p2_ = 0.f, p3_ = 0.f;                            \
    _Pragma("unroll")                                                            \
    for (int k_ = 0; k_ < 4; ++k_) {                                             \
        if (k_ < 3 || has4) {                                                    \
            f32x4 a_ = __builtin_amdgcn_mfma_f32_16x16x32_f16(A0[k_], B0v, zero4, 0,0,0); \
            a_       = __builtin_amdgcn_mfma_f32_16x16x32_f16(A1[k_], B1v, a_,    0,0,0); \
            float ig_ = fsig_p(a_[0]), fg_ = fsig_p(a_[1]);                      \
            float gg_ = ftanhg_p(a_[2]), og_ = fsig_p(a_[3]);                    \
            float c_ = fg_*c1v[k_] + ig_*gg_;                                    \
            c1v[k_] = c_;                                                        \
            int u_ = tiles[k_]*4 + q;                                            \
            if (k_ < 3 || q < 3)   /* u<51; only tile12/q3 is the x-slot */      \
                (HBg)[jl*64 + (((u_>>3) ^ d8) << 3) + (u_&7)] = (f16)(og_*ftanh_c(c_)); \
            FMA_LO(p0_, w2p[k_].x, c_); FMA_HI(p1_, w2p[k_].x, c_);              \
            FMA_LO(p2_, w2p[k_].y, c_); FMA_HI(p3_, w2p[k_].y, c_);              \
        }                                                                        \
    }                                                                            \
    if (w == 0 && q == 3) (HBg)[jl*64 + ((6 ^ d8) << 3) + 3] = xnv;              \
    p0_ += __shfl_xor(p0_, 16); p0_ += __shfl_xor(p0_, 32);                      \
    p1_ += __shfl_xor(p1_, 16); p1_ += __shfl_xor(p1_, 32);                      \
    p2_ += __shfl_xor(p2_, 16); p2_ += __shfl_xor(p2_, 32);                      \
    p3_ += __shfl_xor(p3_, 16); p3_ += __shfl_xor(p3_, 32);                      \
    if (lane < 16) {                                                             \
        f32x4 pv_ = {p0_, p1_, p2_, p3_};                                        \
        *(f32x4*)&(PBLg)[w][jl][0] = pv_;                                        \
    }                                                                            \
} while (0)

__global__ __launch_bounds__(256, 1) void lstm_main(
    const float* __restrict__ X, const f16* __restrict__ Wp, const f16* __restrict__ Wp2,
    const float* __restrict__ Whh2, const float* __restrict__ bih2, const float* __restrict__ bhh2,
    float* __restrict__ out)
{
    // Dual-group software pipeline, 1 block/CU, 4 waves, 2 independent 16-batch groups.
    // Interval schedule: {WRITE_A(t) ∥ READ_B(t)} |bar| {WRITE_B(t) ∥ READ_A(t+1)} |bar|
    // Per group this is exactly R12's read|bar|write|bar discipline (disjoint LDS between
    // groups), and every MFMA's B-operands were loaded one interval earlier (double-buffer).
    __shared__ __align__(16) f16   HBA[1024];
    __shared__ __align__(16) f16   HBB[1024];
    __shared__ __align__(16) float PBLA[4][16][4];
    __shared__ __align__(16) float PBLB[4][16][4];
    __shared__ __align__(16) f16   HX[TT*32];   // [t][row 0..31]: rows 0-15 = A, 16-31 = B

    const int tid  = threadIdx.x;
    const int w    = tid >> 6;
    const int lane = tid & 63;
    const int q    = (lane >> 4) & 3;
    const int jl   = lane & 15;
    const int d8   = jl & 7;
    const int bb32 = blockIdx.x * 32;

    for (int i = tid; i < 512; i += 256) { ((unsigned*)HBA)[i] = 0u; ((unsigned*)HBB)[i] = 0u; }
    { ((unsigned*)PBLA)[tid] = 0u; ((unsigned*)PBLB)[tid] = 0u; }   // 256 dwords each

    // stage X rows bb32..bb32+31 -> HX (f16, [t][row]), coalesced float4 reads
    #pragma unroll
    for (int it = 0; it < 16; ++it) {
        int flat = it*1024 + tid*4;           // over [row][col], 32x512
        int row = flat >> 9, col = flat & 511;
        float4 v = *(const float4*)(X + (size_t)(bb32 + row)*TT + col);
        HX[(col+0)*32 + row] = (f16)v.x;
        HX[(col+1)*32 + row] = (f16)v.y;
        HX[(col+2)*32 + row] = (f16)v.z;
        HX[(col+3)*32 + row] = (f16)v.w;
    }
    __syncthreads();
    if (w == 0 && lane < 16) {                // seed bias (elem 52) + x(0) (elem 51)
        int dd = lane & 7;
        HBA[lane*64 + ((6 ^ dd) << 3) + 4] = (f16)1.f;
        HBB[lane*64 + ((6 ^ dd) << 3) + 4] = (f16)1.f;
        HBA[lane*64 + ((6 ^ dd) << 3) + 3] = HX[0*32 + lane];
        HBB[lane*64 + ((6 ^ dd) << 3) + 3] = HX[0*32 + 16 + lane];
    }

    const bool has4 = (w == 1);               // wave 1 owns tile 12
    const int tiles[4] = { w, 4+w, 8+w, 12 };
    f16x8 A0[4], A1[4];
    uint2 w2p[4];
    #pragma unroll
    for (int k = 0; k < 4; ++k) {
        int m = tiles[k];
        A0[k]  = *(const f16x8*)(Wp + (m*2+0)*512 + lane*8);
        A1[k]  = *(const f16x8*)(Wp + (m*2+1)*512 + lane*8);
        w2p[k] = *(const uint2*)(Wp2 + (m*4+q)*4);
    }
    float wh2[4], bs2[4];
    #pragma unroll
    for (int g = 0; g < 4; ++g) {
        float sc = (g == 2) ? L2E2 : L2E;
        wh2[g] = Whh2[g] * sc;
        bs2[g] = (bih2[g] + bhh2[g]) * sc;
    }

    float c1A[4] = {0.f,0.f,0.f,0.f}, c1B[4] = {0.f,0.f,0.f,0.f};
    float c2A = 0.f, h2A = 0.f, c2B = 0.f, h2B = 0.f;   // live in wave 3
    const f32x4 zero4 = {0.f, 0.f, 0.f, 0.f};

    f16x8 B0A = {}, B1A = {}, B0B = {}, B1B = {};
    f32x4 SA0 = zero4, SA1 = zero4, SA2 = zero4, SA3 = zero4;
    f32x4 SB0 = zero4, SB1 = zero4, SB2 = zero4, SB3 = zero4;
    f16 xnA = (f16)0.f, xnB = (f16)0.f;

    __syncthreads();                           // seeds sealed

    RD_PHASE(HBA, PBLA, 0, 1, B0A, B1A, SA0, SA1, SA2, SA3, xnA);   // READ_A(0)
    __syncthreads();

    for (int t = 0; t < TT; ++t) {
        {   // interval even: READ_B(t) ∥ WRITE_A(t)
            const int tnB = (t+1 < TT) ? t+1 : TT-1;
            RD_PHASE(HBB, PBLB, 16, tnB, B0B, B1B, SB0, SB1, SB2, SB3, xnB);
            WR_PHASE(t > 0, HBA, PBLA, B0A, B1A, SA0, SA1, SA2, SA3, xnA, c1A, c2A, h2A);
            __syncthreads();
        }
        {   // interval odd: READ_A(t+1) ∥ WRITE_B(t)
            const int tnA = (t+2 < TT) ? t+2 : TT-1;
            RD_PHASE(HBA, PBLA, 0, tnA, B0A, B1A, SA0, SA1, SA2, SA3, xnA);
            WR_PHASE(t > 0, HBB, PBLB, B0B, B1B, SB0, SB1, SB2, SB3, xnB, c1B, c2B, h2B);
            __syncthreads();
        }
    }
    // After loop: SA* = PBL_A(511) (read in final R_A); c2/h2 through step 510.
    // HB_G holds h_G(512); PBL_B(511) unread.

    // wave 3: L2_A(511) from SA regs; L2_B(511) from fresh PBLB read; publish c2 -> x-slots
    if (w == 3) {
        {
            f32x4 Ss = SA0 + SA1 + SA2 + SA3;
            float g0 = Ss[0] + bs2[0] + wh2[0]*h2A;
            float g1 = Ss[1] + bs2[1] + wh2[1]*h2A;
            float g2 = Ss[2] + bs2[2] + wh2[2]*h2A;
            float g3 = Ss[3] + bs2[3] + wh2[3]*h2A;
            float i2 = fsig_p(g0), f2 = fsig_p(g1), gg2 = ftanhg_p(g2), o2 = fsig_p(g3);
            c2A = f2*c2A + i2*gg2;
            h2A = o2*ftanh_c(c2A);
        }
        {
            f32x4 Ss = *(const f32x4*)&PBLB[0][jl][0];
            Ss += *(const f32x4*)&PBLB[1][jl][0];
            Ss += *(const f32x4*)&PBLB[2][jl][0];
            Ss += *(const f32x4*)&PBLB[3][jl][0];
            float g0 = Ss[0] + bs2[0] + wh2[0]*h2B;
            float g1 = Ss[1] + bs2[1] + wh2[1]*h2B;
            float g2 = Ss[2] + bs2[2] + wh2[2]*h2B;
            float g3 = Ss[3] + bs2[3] + wh2[3]*h2B;
            float i2 = fsig_p(g0), f2 = fsig_p(g1), gg2 = ftanhg_p(g2), o2 = fsig_p(g3);
            c2B = f2*c2B + i2*gg2;
            h2B = o2*ftanh_c(c2B);
        }
        if (lane < 16) {
            int dd = lane & 7;
            HBA[lane*64 + ((6 ^ dd) << 3) + 3] = (f16)c2A;
            HBB[lane*64 + ((6 ^ dd) << 3) + 3] = (f16)c2B;
        }
    }
    __syncthreads();

    // extra step: lstm1(input = c2_G) -> c1'_G; partials -> PBL_G (no h/x writes)
    {
        const f16* rbA = HBA + jl*64;
        const f16* rbB = HBB + jl*64;
        f16x8 b0a = *(const f16x8*)(rbA + ((q       ^ d8) << 3));
        f16x8 b1a = *(const f16x8*)(rbA + (((4 + q) ^ d8) << 3));
        f16x8 b0b = *(const f16x8*)(rbB + ((q       ^ d8) << 3));
        f16x8 b1b = *(const f16x8*)(rbB + (((4 + q) ^ d8) << 3));

        float pA0=0.f, pA1=0.f, pA2=0.f, pA3=0.f;
        float pB0=0.f, pB1=0.f, pB2=0.f, pB3=0.f;
        #pragma unroll
        for (int k = 0; k < 4; ++k) {
            if (k < 3 || has4) {
                f32x4 aA = __builtin_amdgcn_mfma_f32_16x16x32_f16(A0[k], b0a, zero4, 0,0,0);
                aA       = __builtin_amdgcn_mfma_f32_16x16x32_f16(A1[k], b1a, aA,    0,0,0);
                f32x4 aB = __builtin_amdgcn_mfma_f32_16x16x32_f16(A0[k], b0b, zero4, 0,0,0);
                aB       = __builtin_amdgcn_mfma_f32_16x16x32_f16(A1[k], b1b, aB,    0,0,0);
                {
                    float ig = fsig_p(aA[0]), fg = fsig_p(aA[1]), gg = ftanhg_p(aA[2]);
                    float c  = fg*c1A[k] + ig*gg;
                    FMA_LO(pA0, w2p[k].x, c); FMA_HI(pA1, w2p[k].x, c);
                    FMA_LO(pA2, w2p[k].y, c); FMA_HI(pA3, w2p[k].y, c);
                }
                {
                    float ig = fsig_p(aB[0]), fg = fsig_p(aB[1]), gg = ftanhg_p(aB[2]);
                    float c  = fg*c1B[k] + ig*gg;
                    FMA_LO(pB0, w2p[k].x, c); FMA_HI(pB1, w2p[k].x, c);
                    FMA_LO(pB2, w2p[k].y, c); FMA_HI(pB3, w2p[k].y, c);
                }
            }
        }
        pA0 += __shfl_xor(pA0, 16); pA0 += __shfl_xor(pA0, 32);
        pA1 += __shfl_xor(pA1, 16); pA1 += __shfl_xor(pA1, 32);
        pA2 += __shfl_xor(pA2, 16); pA2 += __shfl_xor(pA2, 32);
        pB0 += __shfl_xor(pB0, 16); pB0 += __shfl_xor(pB0, 32);
        pB1 += __shfl_xor(pB1, 16); pB1 += __shfl_xor(pB1, 32);
        pB2 += __shfl_xor(pB2, 16); pB2 += __shfl_xor(pB2, 32);
        if (lane < 16) {
            f32x4 pa = {pA0, pA1, pA2, 0.f};
            f32x4 pb = {pB0, pB1, pB2, 0.f};
            *(f32x4*)&PBLA[w][jl][0] = pa;
            *(f32x4*)&PBLB[w][jl][0] = pb;
        }
    }
    __syncthreads();

    // final: lstm2 gates on c1' -> out = new c2 (both groups)
    if (w == 3) {
        {
            f32x4 Ss = *(const f32x4*)&PBLA[0][jl][0];
            Ss += *(const f32x4*)&PBLA[1][jl][0];
            Ss += *(const f32x4*)&PBLA[2][jl][0];
            Ss += *(const f32x4*)&PBLA[3][jl][0];
            float g0 = Ss[0] + bs2[0] + wh2[0]*h2A;
            float g1 = Ss[1] + bs2[1] + wh2[1]*h2A;
            float g2 = Ss[2] + bs2[2] + wh2[2]*h2A;
            float i2 = fsig_p(g0), f2 = fsig_p(g1), gg2 = ftanhg_p(g2);
            float c2n = f2*c2A + i2*gg2;
            if (lane < 16) out[bb32 + jl] = c2n;
        }
        {
            f32x4 Ss = *(const f32x4*)&PBLB[0][jl][0];
            Ss += *(const f32x4*)&PBLB[1][jl][0];
            Ss += *(const f32x4*)&PBLB[2][jl][0];
            Ss += *(const f32x4*)&PBLB[3][jl][0];
            float g0 = Ss[0] + bs2[0] + wh2[0]*h2B;
            float g1 = Ss[1] + bs2[1] + wh2[1]*h2B;
            float g2 = Ss[2] + bs2[2] + wh2[2]*h2B;
            float i2 = fsig_p(g0), f2 = fsig_p(g1), gg2 = ftanhg_p(g2);
            float c2n = f2*c2B + i2*gg2;
            if (lane < 16) out[bb32 + 16 + jl] = c2n;
        }
    }
}

extern "C" void kernel_launch(void* const* d_in, const int* in_sizes, int n_in,
                              void* d_out, int out_size, void* d_ws, size_t ws_size,
                              hipStream_t stream) {
    const float* X    = (const float*)d_in[0];
    const float* Wih1 = (const float*)d_in[1];
    const float* Whh1 = (const float*)d_in[2];
    const float* bih1 = (const float*)d_in[3];
    const float* bhh1 = (const float*)d_in[4];
    const float* Wih2 = (const float*)d_in[5];
    const float* Whh2 = (const float*)d_in[6];
    const float* bih2 = (const float*)d_in[7];
    const float* bhh2 = (const float*)d_in[8];
    float* out = (float*)d_out;

    f16* Wp  = (f16*)d_ws;                      // 13312 f16 = 26624 B
    f16* Wp2 = (f16*)((char*)d_ws + 26624);     // 224 f16

    repack_w<<<52, 256, 0, stream>>>(Whh1, Wih1, bih1, bhh1, Wih2, Wp, Wp2);
    lstm_main<<<256, 256, 0, stream>>>(X, Wp, Wp2, Whh2, bih2, bhh2, out);
}

// Round 17
// 435.346 us; speedup vs baseline: 1.4481x; 1.4481x over previous
//
#include <hip/hip_runtime.h>

#define TT 512
#define L2E  1.4426950408889634f
#define L2E2 2.8853900817779268f

typedef _Float16 f16;
typedef _Float16 f16x8 __attribute__((ext_vector_type(8)));
typedef float f32x4 __attribute__((ext_vector_type(4)));

// prescaled-arg nonlinearities (arg already multiplied by log2e / 2log2e)
__device__ __forceinline__ float fsig_p(float a){          // sigmoid, a = x*log2e
    return __builtin_amdgcn_rcpf(1.f + __builtin_amdgcn_exp2f(-a));
}
__device__ __forceinline__ float ftanhg_p(float a){        // tanh, a = x*2log2e
    return 2.f * __builtin_amdgcn_rcpf(1.f + __builtin_amdgcn_exp2f(-a)) - 1.f;
}
__device__ __forceinline__ float ftanh_c(float c){         // tanh, unscaled input
    return 2.f * __builtin_amdgcn_rcpf(1.f + __builtin_amdgcn_exp2f(-L2E2*c)) - 1.f;
}

// v_fma_mix_f32: dst.f32 += f16(src0 lo/hi) * f32(src1)
#define FMA_LO(accv, wd, hh) asm("v_fma_mix_f32 %0, %1, %2, %0 op_sel:[0,0,0] op_sel_hi:[1,0,0]" : "+v"(accv) : "v"(wd), "v"(hh))
#define FMA_HI(accv, wd, hh) asm("v_fma_mix_f32 %0, %1, %2, %0 op_sel:[1,0,0] op_sel_hi:[1,0,0]" : "+v"(accv) : "v"(wd), "v"(hh))

// Wp (f16): [13 m][2 kt][64 lane][8 b] A-fragments for mfma_f32_16x16x32_f16
//   row r = m*16 + (lane&15), r = 4*u+g unit-major; k = kt*32 + (lane>>4)*8 + b
//   col 0..50 = Whh1; col 51 = Wih1; col 52 = bih1+bhh1; col 53..63 = 0; rows u>=51 all 0
//   ALL row values prescaled by log2e (gates i,f,o) or 2log2e (gate g) for exp2-direct.
// Wp2 (f16): [56 u][4 g] = Wih2[g*51+u] prescaled the same way, zero-padded
__global__ void repack_w(const float* __restrict__ Whh1, const float* __restrict__ Wih1,
                         const float* __restrict__ bih1, const float* __restrict__ bhh1,
                         const float* __restrict__ Wih2,
                         f16* __restrict__ Wp, f16* __restrict__ Wp2)
{
    int i = blockIdx.x*256 + threadIdx.x;
    if (i < 13*2*64*8) {
        int b    = i & 7;
        int lane = (i >> 3) & 63;
        int kt   = (i >> 9) & 1;
        int m    = i >> 10;
        int r = m*16 + (lane & 15);
        int u = r >> 2, g = r & 3;
        int k = kt*32 + (lane >> 4)*8 + b;
        float v = 0.f;
        if (u < 51) {
            int rt = g*51 + u;
            if      (k < 51)  v = Whh1[rt*51 + k];
            else if (k == 51) v = Wih1[rt];
            else if (k == 52) v = bih1[rt] + bhh1[rt];
            v *= (g == 2) ? L2E2 : L2E;
        }
        Wp[i] = (f16)v;
    }
    if (i < 224) {
        int u = i >> 2, g = i & 3;
        float v = (u < 51) ? Wih2[g*51 + u] : 0.f;
        v *= (g == 2) ? L2E2 : L2E;
        Wp2[i] = (f16)v;
    }
}

__global__ __launch_bounds__(256, 2) void lstm_main(
    const float* __restrict__ X, const f16* __restrict__ Wp, const f16* __restrict__ Wp2,
    const float* __restrict__ Whh2, const float* __restrict__ bih2, const float* __restrict__ bhh2,
    float* __restrict__ out)
{
    // Single-buffer state. Discipline: READ phase | barrier A | WRITE phase | barrier B.
    // HB:  [jl][64] f16; 8-elem groups XOR-swizzled: elem e at (e&7) | (((e>>3)^(jl&7))<<3)
    // PBL: [wave][jl] f32x4 layer-2 gate partials
    // HX:  [t][jl] f16 — the block's entire X slice, staged once (NO global loads in loop)
    __shared__ __align__(16) f16   HB[1024];
    __shared__ __align__(16) float PBL[4][16][4];
    __shared__ __align__(16) f16   HX[TT*16];

    const int tid  = threadIdx.x;
    const int w    = tid >> 6;         // wave 0..3
    const int lane = tid & 63;
    const int q    = (lane >> 4) & 3;
    const int jl   = lane & 15;
    const int d8   = jl & 7;
    const int bb   = blockIdx.x * 16;

    for (int i = tid; i < 512; i += 256) ((unsigned*)HB)[i] = 0u;
    if (tid < 256) ((unsigned*)PBL)[tid] = 0u;

    // ---- stage X -> HX (f16, [t][row] layout), coalesced float4 reads ----
    #pragma unroll
    for (int it = 0; it < 8; ++it) {
        int flat = it*1024 + tid*4;            // 0..8191 over [row][col] row-major
        int row = flat >> 9, col = flat & 511;
        float4 v = *(const float4*)(X + (size_t)(bb + row)*TT + col);
        HX[(col+0)*16 + row] = (f16)v.x;
        HX[(col+1)*16 + row] = (f16)v.y;
        HX[(col+2)*16 + row] = (f16)v.z;
        HX[(col+3)*16 + row] = (f16)v.w;
    }
    __syncthreads();
    if (w == 0 && lane < 16) {         // seed bias slot (elem 52) and x(0) (elem 51)
        int dd = lane & 7;
        HB[lane*64 + ((6 ^ dd) << 3) + 4] = (f16)1.f;
        HB[lane*64 + ((6 ^ dd) << 3) + 3] = HX[0*16 + lane];
    }

    const bool has4 = (w == 1);        // wave 1 owns tile 12
    const int tiles[4] = {w, 4+w, 8+w, 12};
    f16x8 A0[4], A1[4];
    uint2 w2p[4];
    #pragma unroll
    for (int k = 0; k < 4; ++k) {
        int m = tiles[k];
        A0[k]  = *(const f16x8*)(Wp + (m*2+0)*512 + lane*8);
        A1[k]  = *(const f16x8*)(Wp + (m*2+1)*512 + lane*8);
        w2p[k] = *(const uint2*)(Wp2 + (m*4+q)*4);
    }
    float wh2[4], bs2[4];
    #pragma unroll
    for (int g = 0; g < 4; ++g) {
        float sc = (g == 2) ? L2E2 : L2E;
        wh2[g] = Whh2[g] * sc;
        bs2[g] = (bih2[g] + bhh2[g]) * sc;
    }

    float c1[4] = {0.f, 0.f, 0.f, 0.f};
    float c2 = 0.f, h2 = 0.f;          // live in wave 3 (all lanes redundant)
    const f32x4 zero4 = {0.f, 0.f, 0.f, 0.f};

    __syncthreads();

    for (int t = 0; t < TT; ++t) {
        // ---------- READ phase ----------
        const f16* rb = HB + jl*64;
        f16x8 B0 = *(const f16x8*)(rb + ((q       ^ d8) << 3));
        f16x8 B1 = *(const f16x8*)(rb + (((4 + q) ^ d8) << 3));

        f32x4 S0, S1, S2, S3;
        if (w == 3) {                   // layer-2 partials of step t-1 (zeros at t=0)
            S0 = *(const f32x4*)&PBL[0][jl][0];
            S1 = *(const f32x4*)&PBL[1][jl][0];
            S2 = *(const f32x4*)&PBL[2][jl][0];
            S3 = *(const f32x4*)&PBL[3][jl][0];
        }

        __syncthreads();                // A: all reads complete

        // ---------- WRITE phase ----------
        if (w == 3 && t > 0) {          // layer-2 LSTM for step t-1 (register-only)
            f32x4 S = S0 + S1 + S2 + S3;
            float g0 = S[0] + bs2[0] + wh2[0]*h2;
            float g1 = S[1] + bs2[1] + wh2[1]*h2;
            float g2 = S[2] + bs2[2] + wh2[2]*h2;
            float g3 = S[3] + bs2[3] + wh2[3]*h2;
            float i2 = fsig_p(g0), f2 = fsig_p(g1), gg2 = ftanhg_p(g2), o2 = fsig_p(g3);
            c2 = f2*c2 + i2*gg2;
            h2 = o2*ftanh_c(c2);
        }

        float p0 = 0.f, p1 = 0.f, p2 = 0.f, p3 = 0.f;
        #pragma unroll
        for (int k = 0; k < 4; ++k) {
            if (k < 3 || has4) {
                f32x4 a = __builtin_amdgcn_mfma_f32_16x16x32_f16(A0[k], B0, zero4, 0,0,0);
                a       = __builtin_amdgcn_mfma_f32_16x16x32_f16(A1[k], B1, a,     0,0,0);
                float ig = fsig_p(a[0]), fg = fsig_p(a[1]), gg = ftanhg_p(a[2]), og = fsig_p(a[3]);
                float c  = fg*c1[k] + ig*gg;
                c1[k] = c;
                int u = tiles[k]*4 + q;
                if (k < 3 || q < 3)     // u<51 (tile12/q3 is the x-slot, not a unit)
                    HB[jl*64 + (((u >> 3) ^ d8) << 3) + (u & 7)] = (f16)(og * ftanh_c(c));
                FMA_LO(p0, w2p[k].x, c); FMA_HI(p1, w2p[k].x, c);
                FMA_LO(p2, w2p[k].y, c); FMA_HI(p3, w2p[k].y, c);
            }
        }
        if (w == 0 && q == 3)           // x(t+1) -> elem 51 (LDS->LDS, no vmcnt)
            HB[jl*64 + ((6 ^ d8) << 3) + 3] = HX[((t+1 < TT) ? t+1 : 0)*16 + jl];

        p0 += __shfl_xor(p0, 16); p0 += __shfl_xor(p0, 32);
        p1 += __shfl_xor(p1, 16); p1 += __shfl_xor(p1, 32);
        p2 += __shfl_xor(p2, 16); p2 += __shfl_xor(p2, 32);
        p3 += __shfl_xor(p3, 16); p3 += __shfl_xor(p3, 32);
        if (lane < 16) {
            f32x4 pv = {p0, p1, p2, p3};
            *(f32x4*)&PBL[w][jl][0] = pv;
        }
        __syncthreads();                // B: all writes sealed
    }
    // HB holds h(512) + slot52 bias; PBL holds step-511 partials; c2/h2 through step 510.

    // wave 3: layer-2 for step 511, publish c2 into elem-51 slot
    if (w == 3) {
        f32x4 S = *(const f32x4*)&PBL[0][jl][0];
        S += *(const f32x4*)&PBL[1][jl][0];
        S += *(const f32x4*)&PBL[2][jl][0];
        S += *(const f32x4*)&PBL[3][jl][0];
        float g0 = S[0] + bs2[0] + wh2[0]*h2;
        float g1 = S[1] + bs2[1] + wh2[1]*h2;
        float g2 = S[2] + bs2[2] + wh2[2]*h2;
        float g3 = S[3] + bs2[3] + wh2[3]*h2;
        float i2 = fsig_p(g0), f2 = fsig_p(g1), gg2 = ftanhg_p(g2), o2 = fsig_p(g3);
        c2 = f2*c2 + i2*gg2;
        h2 = o2*ftanh_c(c2);
        if (lane < 16) HB[jl*64 + ((6 ^ d8) << 3) + 3] = (f16)c2;
    }
    __syncthreads();                    // C

    // extra step: lstm1(input = c2) -> c1'; partials -> PBL
    {
        const f16* rb = HB + jl*64;
        f16x8 B0 = *(const f16x8*)(rb + ((q       ^ d8) << 3));
        f16x8 B1 = *(const f16x8*)(rb + (((4 + q) ^ d8) << 3));

        float p0 = 0.f, p1 = 0.f, p2 = 0.f, p3 = 0.f;
        #pragma unroll
        for (int k = 0; k < 4; ++k) {
            if (k < 3 || has4) {
                f32x4 a = __builtin_amdgcn_mfma_f32_16x16x32_f16(A0[k], B0, zero4, 0,0,0);
                a       = __builtin_amdgcn_mfma_f32_16x16x32_f16(A1[k], B1, a,     0,0,0);
                float ig = fsig_p(a[0]), fg = fsig_p(a[1]), gg = ftanhg_p(a[2]);
                float c  = fg*c1[k] + ig*gg;
                FMA_LO(p0, w2p[k].x, c); FMA_HI(p1, w2p[k].x, c);
                FMA_LO(p2, w2p[k].y, c); FMA_HI(p3, w2p[k].y, c);
            }
        }
        p0 += __shfl_xor(p0, 16); p0 += __shfl_xor(p0, 32);
        p1 += __shfl_xor(p1, 16); p1 += __shfl_xor(p1, 32);
        p2 += __shfl_xor(p2, 16); p2 += __shfl_xor(p2, 32);
        p3 += __shfl_xor(p3, 16); p3 += __shfl_xor(p3, 32);
        if (lane < 16) {
            f32x4 pv = {p0, p1, p2, p3};
            *(f32x4*)&PBL[w][jl][0] = pv;
        }
    }
    __syncthreads();                    // D

    // final: lstm2 gates on c1' -> out = new c2
    if (w == 3) {
        f32x4 S = *(const f32x4*)&PBL[0][jl][0];
        S += *(const f32x4*)&PBL[1][jl][0];
        S += *(const f32x4*)&PBL[2][jl][0];
        S += *(const f32x4*)&PBL[3][jl][0];
        float g0 = S[0] + bs2[0] + wh2[0]*h2;
        float g1 = S[1] + bs2[1] + wh2[1]*h2;
        float g2 = S[2] + bs2[2] + wh2[2]*h2;
        float i2 = fsig_p(g0), f2 = fsig_p(g1), gg2 = ftanhg_p(g2);
        float c2n = f2*c2 + i2*gg2;
        if (lane < 16) out[bb + jl] = c2n;
    }
}

extern "C" void kernel_launch(void* const* d_in, const int* in_sizes, int n_in,
                              void* d_out, int out_size, void* d_ws, size_t ws_size,
                              hipStream_t stream) {
    const float* X    = (const float*)d_in[0];
    const float* Wih1 = (const float*)d_in[1];
    const float* Whh1 = (const float*)d_in[2];
    const float* bih1 = (const float*)d_in[3];
    const float* bhh1 = (const float*)d_in[4];
    const float* Wih2 = (const float*)d_in[5];
    const float* Whh2 = (const float*)d_in[6];
    const float* bih2 = (const float*)d_in[7];
    const float* bhh2 = (const float*)d_in[8];
    float* out = (float*)d_out;

    f16* Wp  = (f16*)d_ws;                      // 13312 f16 = 26624 B
    f16* Wp2 = (f16*)((char*)d_ws + 26624);     // 224 f16

    repack_w<<<52, 256, 0, stream>>>(Whh1, Wih1, bih1, bhh1, Wih2, Wp, Wp2);
    lstm_main<<<512, 256, 0, stream>>>(X, Wp, Wp2, Whh2, bih2, bhh2, out);
}